// Round 7
// baseline (510.343 us; speedup 1.0000x reference)
//
#include <hip/hip_runtime.h>

// LSTMModel: 4-layer LSTM (H=50, IN=7, B=1024, T=512) + FC(50->25 relu ->1).
// R7: issue-count reduction on the R6 skeleton.
//  - Ring-integrated layer 0: Xring[64][4][80], row = [x(t) 0..6 | 1.0 at 7 |
//    h0(t-1) at 8..57]. Layer 0: 2 ds_reads + 8 MFMAs (K=64). h0(t) written
//    to row (t+1)&63. Layer 1 reads the same ring row (A maps k=8..57 ->
//    Wih1[:,k-8], k==7 -> bias1, k<7 -> 0). Hbuf[0] eliminated.
//  - Paired reciprocals in the cell update: rcp(di*df), rcp(dg*do) -> 8 trans
//    ops per update lane (was 10).
//  - Persistent zero accumulator (no per-tick acc init).
//  - Row stride 80 halves everywhere (40 dw = 8 mod 32: <=2-way, free).
// Layers 2,3 unchanged: parity-double-buffered Hbuf[l], bias-1.0 at slot 56.

#define H 50
#define INSZ 7
#define TT 512
#define NL 4
#define FC1N 25
#define BPG 4
#define NBLK 256
#define NTHREADS 1024
#define HS 80         // row stride in halves
#define RROW (BPG * HS)  // ring row group stride in halves (320)
#define BIASL 56

typedef _Float16 half_t;
typedef __attribute__((ext_vector_type(8))) _Float16 half8_t;
typedef __attribute__((ext_vector_type(4))) float float4_t;

struct Params {
  const float* x;
  const float* Wih[NL];
  const float* Whh[NL];
  const float* bih[NL];
  const float* bhh[NL];
  const float* W1;
  const float* b1;
  const float* W2;
  const float* b2;
  float* out;
};

#define MFMA16(A, B, C) __builtin_amdgcn_mfma_f32_16x16x32_f16((A), (B), (C), 0, 0, 0)
#define EXP2F(x) __builtin_amdgcn_exp2f(x)
#define RCPF(x) __builtin_amdgcn_rcpf(x)

__global__ __launch_bounds__(NTHREADS, 4) void lstm_r7(Params p) {
  __shared__ __align__(16) half_t Xring[64][BPG][HS];      // 40 KB ring (L0+L1)
  __shared__ __align__(16) half_t Hbuf[NL - 1][2][BPG][HS]; // layers 1..3 own-h
  __shared__ float fc_h[BPG][H];
  __shared__ float fc1_buf[BPG][FC1N];

  const int tid = threadIdx.x;
  const int b0 = blockIdx.x * BPG;
  const int lane = tid & 63;
  const int quad = lane >> 4;
  const int col = lane & 15;
  const int glay = tid >> 8;                     // layer (4 waves each)
  const int wl = (((tid >> 6) & 3) + glay) & 3;  // M-chunk, SIMD-balanced

  // ---- A fragments: row r = wl*64 + t4*16 + col (unit-major r=4u+q),
  //      k = g*32 + quad*8 + j.
  half8_t afrag[4][4];
#pragma unroll
  for (int t4 = 0; t4 < 4; ++t4) {
#pragma unroll
    for (int g = 0; g < 4; ++g) {
      half8_t v;
#pragma unroll
      for (int j = 0; j < 8; ++j) {
        const int r = wl * 64 + t4 * 16 + col;
        const int u = r >> 2, q = r & 3;
        const int k = g * 32 + quad * 8 + j;
        float wv = 0.0f;
        if (u < H) {
          const int row = q * H + u;
          if (glay == 0) {           // K=64: x 0..6, bias 7, own-h 8..57
            if (k < INSZ) wv = p.Wih[0][row * INSZ + k];
            else if (k == 7) wv = p.bih[0][row] + p.bhh[0][row];
            else if (k >= 8 && k < 8 + H) wv = p.Whh[0][row * H + (k - 8)];
          } else if (glay == 1) {    // in-h from ring at 8..57, bias at 7
            if (k == 7) wv = p.bih[1][row] + p.bhh[1][row];
            else if (k >= 8 && k < 8 + H) wv = p.Wih[1][row * H + (k - 8)];
            else if (k >= 64 && k < 64 + H) wv = p.Whh[1][row * H + (k - 64)];
          } else {                   // in-h 0..49, bias 56, own-h 64..113
            if (k < H) wv = p.Wih[glay][row * H + k];
            else if (k == BIASL) wv = p.bih[glay][row] + p.bhh[glay][row];
            else if (k >= 64 && k < 64 + H) wv = p.Whh[glay][row * H + (k - 64)];
          }
        }
        v[j] = (half_t)wv;
      }
      afrag[t4][g] = v;
    }
  }

  // ---- init LDS ----
  {
    unsigned* xz = (unsigned*)Xring;
    const int nx = 64 * BPG * HS / 2;
    for (int i = tid; i < nx; i += NTHREADS) xz[i] = 0u;
    unsigned* hz = (unsigned*)Hbuf;
    const int nh = (NL - 1) * 2 * BPG * HS / 2;
    for (int i = tid; i < nh; i += NTHREADS) hz[i] = 0u;
  }
  __syncthreads();
  // bias-1.0 slots
  for (int i = tid; i < 64 * BPG; i += NTHREADS)  // ring: every row, slot 7
    Xring[i >> 2][i & 3][7] = (half_t)1.0f;
  if (tid < (NL - 1) * 2 * BPG) {                 // Hbuf: slot 56
    const int l = tid >> 3, pr = (tid >> 2) & 1, b = tid & 3;
    Hbuf[l][pr][b][BIASL] = (half_t)1.0f;
  }
  // initial ring x fill: t = 0..63
  for (int i = tid; i < 64 * BPG * INSZ; i += NTHREADS) {
    const int t = i / (BPG * INSZ), rem = i % (BPG * INSZ);
    const int b = rem / INSZ, k = rem % INSZ;
    Xring[t][b][k] = (half_t)p.x[((size_t)(b0 + b) * TT + t) * INSZ + k];
  }
  __syncthreads();

  // ---- per-lane roles ----
  const int bb = col & 3;
  const int tsel = col >> 2;
  const int uu = 16 * wl + 4 * tsel + quad;
  const bool updact = (uu < H);

  // ring bases (per-lane)
  const half_t* ring_rd0 = &Xring[0][bb][quad * 8];
  half_t* ring_st0 = &Xring[0][bb][8 + uu];

  // parity pointers for layers >= 1 (own sections); input for layers >= 2
  const half_t* inb[2] = {nullptr, nullptr};
  const half_t* ownb[2] = {nullptr, nullptr};
  half_t* stb[2] = {nullptr, nullptr};
  if (glay >= 1) {
    ownb[0] = &Hbuf[glay - 1][0][bb][quad * 8];
    ownb[1] = &Hbuf[glay - 1][1][bb][quad * 8];
    stb[0] = &Hbuf[glay - 1][1][bb][uu];   // write par^1
    stb[1] = &Hbuf[glay - 1][0][bb][uu];
  }
  if (glay >= 2) {
    inb[0] = &Hbuf[glay - 2][1][bb][quad * 8];  // h_{l-1}(t) at par^1
    inb[1] = &Hbuf[glay - 2][0][bb][quad * 8];
  }
  const int pe = glay & 1, po = pe ^ 1;  // par at even / odd s
  const half_t* in_e = inb[pe];
  const half_t* in_o = inb[po];
  const half_t* own_e = ownb[pe];
  const half_t* own_o = ownb[po];
  half_t* st_e = stb[pe];
  half_t* st_o = stb[po];

  // x refill role: layer-0 wl==3 wave
  const bool xwave = (glay == 0) && (wl == 3);
  const int rb = lane >> 5;
  const int rt = lane & 31;

  float cst = 0.0f;
  const float4_t fzc = {0.0f, 0.0f, 0.0f, 0.0f};

#define TICK_BODY(PIN, POWN, PST, FCW)                                          \
  {                                                                             \
    float4_t a0 = fzc, a1 = fzc, a2 = fzc, a3 = fzc;                            \
    if (glay == 0) {                                                            \
      const half8_t v0 = *(const half8_t*)(PIN);                                \
      const half8_t v1 = *(const half8_t*)((PIN) + 32);                         \
      if (wl != 3) {                                                            \
        a0 = MFMA16(afrag[0][0], v0, a0); a1 = MFMA16(afrag[1][0], v0, a1);     \
        a2 = MFMA16(afrag[2][0], v0, a2); a3 = MFMA16(afrag[3][0], v0, a3);     \
        a0 = MFMA16(afrag[0][1], v1, a0); a1 = MFMA16(afrag[1][1], v1, a1);     \
        a2 = MFMA16(afrag[2][1], v1, a2); a3 = MFMA16(afrag[3][1], v1, a3);     \
      } else {                                                                  \
        a0 = MFMA16(afrag[0][0], v0, a0);                                       \
        a0 = MFMA16(afrag[0][1], v1, a0);                                       \
      }                                                                         \
    } else {                                                                    \
      const half8_t v0 = *(const half8_t*)(PIN);                                \
      const half8_t v1 = *(const half8_t*)((PIN) + 32);                         \
      const half8_t v2 = *(const half8_t*)(POWN);                               \
      const half8_t v3 = *(const half8_t*)((POWN) + 32);                        \
      if (wl != 3) {                                                            \
        a0 = MFMA16(afrag[0][0], v0, a0); a1 = MFMA16(afrag[1][0], v0, a1);     \
        a2 = MFMA16(afrag[2][0], v0, a2); a3 = MFMA16(afrag[3][0], v0, a3);     \
        a0 = MFMA16(afrag[0][1], v1, a0); a1 = MFMA16(afrag[1][1], v1, a1);     \
        a2 = MFMA16(afrag[2][1], v1, a2); a3 = MFMA16(afrag[3][1], v1, a3);     \
        a0 = MFMA16(afrag[0][2], v2, a0); a1 = MFMA16(afrag[1][2], v2, a1);     \
        a2 = MFMA16(afrag[2][2], v2, a2); a3 = MFMA16(afrag[3][2], v2, a3);     \
        a0 = MFMA16(afrag[0][3], v3, a0); a1 = MFMA16(afrag[1][3], v3, a1);     \
        a2 = MFMA16(afrag[2][3], v3, a2); a3 = MFMA16(afrag[3][3], v3, a3);     \
      } else {                                                                  \
        a0 = MFMA16(afrag[0][0], v0, a0);                                       \
        a0 = MFMA16(afrag[0][1], v1, a0);                                       \
        a0 = MFMA16(afrag[0][2], v2, a0);                                       \
        a0 = MFMA16(afrag[0][3], v3, a0);                                       \
      }                                                                         \
    }                                                                           \
    if (updact) {                                                               \
      const float4_t g01 = (col & 4) ? a1 : a0;                                 \
      const float4_t g23 = (col & 4) ? a3 : a2;                                 \
      const float4_t ga = (col & 8) ? g23 : g01;                                \
      const float di = 1.0f + EXP2F(-1.442695041f * ga[0]);                     \
      const float df = 1.0f + EXP2F(-1.442695041f * ga[1]);                     \
      const float dg = 1.0f + EXP2F(-2.885390082f * ga[2]);                     \
      const float dq = 1.0f + EXP2F(-1.442695041f * ga[3]);                     \
      const float r1 = RCPF(di * df);                                           \
      const float r2 = RCPF(dg * dq);                                           \
      const float gi = r1 * df;                                                 \
      const float gf = r1 * di;                                                 \
      const float gg = 2.0f * (r2 * dq) - 1.0f;                                 \
      const float go = r2 * dg;                                                 \
      cst = gf * cst + gi * gg;                                                 \
      const float dc = 1.0f + EXP2F(-2.885390082f * cst);                       \
      const float h = go * (2.0f * RCPF(dc) - 1.0f);                            \
      *(PST) = (half_t)h;                                                       \
      if (FCW) fc_h[bb][uu] = h;                                                \
    }                                                                           \
  }

  // ---- prologue: s = 0..2 ----
  for (int s = 0; s < 3; ++s) {
    const int t = s - glay;
    if (t >= 0) {
      const half_t* rd = ring_rd0 + (s & 63) * RROW;
      half_t* rst = ring_st0 + ((s + 1) & 63) * RROW;
      const int par = t & 1;
      const half_t* pin = (glay <= 1) ? rd : inb[par];
      const half_t* pown = (glay >= 1) ? ownb[par] : rd;
      half_t* pst = (glay == 0) ? rst : stb[par];
      TICK_BODY(pin, pown, pst, false)
    }
    __syncthreads();
  }

  // ---- steady: s = 3..510, unrolled x2 ----
  for (int s = 3; s < 511; s += 2) {
    {  // odd tick s
      const half_t* rd = ring_rd0 + (s & 63) * RROW;
      half_t* rst = ring_st0 + ((s + 1) & 63) * RROW;
      const half_t* pin = (glay <= 1) ? rd : in_o;
      const half_t* pown = (glay >= 1) ? own_o : rd;
      half_t* pst = (glay == 0) ? rst : st_o;
      TICK_BODY(pin, pown, pst, false)
    }
    __syncthreads();
    {  // even tick s+1
      const int s2 = s + 1;
      if (xwave && (s2 & 31) == 8 && s2 < 480) {  // ring refill (hidden)
        const int tb = (s2 & ~31) + 32;
#pragma unroll
        for (int pp = 0; pp < 2; ++pp) {
          const int b = rb + 2 * pp;
          const int t = tb + rt;
          const float* src = &p.x[((size_t)(b0 + b) * TT + t) * INSZ];
          half_t* dst = &Xring[t & 63][b][0];
#pragma unroll
          for (int k = 0; k < INSZ; ++k) dst[k] = (half_t)src[k];
        }
      }
      const half_t* rd = ring_rd0 + (s2 & 63) * RROW;
      half_t* rst = ring_st0 + ((s2 + 1) & 63) * RROW;
      const half_t* pin = (glay <= 1) ? rd : in_e;
      const half_t* pown = (glay >= 1) ? own_e : rd;
      half_t* pst = (glay == 0) ? rst : st_e;
      TICK_BODY(pin, pown, pst, false)
    }
    __syncthreads();
  }

  // ---- tail: s = 511..514 ----
  for (int s = 511; s < TT + NL - 1; ++s) {
    const int t = s - glay;
    if (t < TT) {
      const half_t* rd = ring_rd0 + (s & 63) * RROW;
      half_t* rst = ring_st0 + ((s + 1) & 63) * RROW;
      const int par = t & 1;
      const half_t* pin = (glay <= 1) ? rd : inb[par];
      const half_t* pown = (glay >= 1) ? ownb[par] : rd;
      half_t* pst = (glay == 0) ? rst : stb[par];
      const bool fcw = (glay == NL - 1) && (t == TT - 1);
      TICK_BODY(pin, pown, pst, fcw)
    }
    __syncthreads();
  }

  // ---- FC head (fp32) ----
  if (tid < BPG * FC1N) {
    const int b = tid / FC1N, j = tid % FC1N;
    const float* w = p.W1 + j * H;
    float a = p.b1[j];
#pragma unroll
    for (int k = 0; k < H; ++k) a += fc_h[b][k] * w[k];
    fc1_buf[b][j] = fmaxf(a, 0.0f);
  }
  __syncthreads();
  if (tid < BPG) {
    float a = p.b2[0];
#pragma unroll
    for (int j = 0; j < FC1N; ++j) a += fc1_buf[tid][j] * p.W2[j];
    p.out[b0 + tid] = a;
  }
}

extern "C" void kernel_launch(void* const* d_in, const int* in_sizes, int n_in,
                              void* d_out, int out_size, void* d_ws, size_t ws_size,
                              hipStream_t stream) {
  Params p;
  p.x = (const float*)d_in[0];
  for (int l = 0; l < NL; ++l) {
    p.Wih[l] = (const float*)d_in[1 + 4 * l];
    p.Whh[l] = (const float*)d_in[2 + 4 * l];
    p.bih[l] = (const float*)d_in[3 + 4 * l];
    p.bhh[l] = (const float*)d_in[4 + 4 * l];
  }
  p.W1 = (const float*)d_in[17];
  p.b1 = (const float*)d_in[18];
  p.W2 = (const float*)d_in[19];
  p.b2 = (const float*)d_in[20];
  p.out = (float*)d_out;

  hipLaunchKernelGGL(lstm_r7, dim3(NBLK), dim3(NTHREADS), 0, stream, p);
}

// Round 8
// 474.922 us; speedup vs baseline: 1.0746x; 1.0746x over previous
//
#include <hip/hip_runtime.h>

// LSTMModel: 4-layer LSTM (H=50, IN=7, B=1024, T=512) + FC(50->25 relu ->1).
// R8 = R6 (best, 490us) + R7's wins delivered without register-pressure spill:
//  - Xpack[2][4][80]: row = [x(t) 0..6 | 1.0 at 7 | h0(t-1) at 8..57].
//    L0 reads 2xb128, runs 8 MFMAs (K=64). L1 reads the SAME row as input
//    (A: k=7->bias1, k=8..57->Wih1), so Hbuf[0]-for-input is gone.
//    x(s+1) copied ring->Xpack[(s+1)&1] each tick by ONE light wave (28 lanes,
//    1 ds_read_u16 + 1 ds_write_b16); no per-tick pointers on MFMA waves.
//  - uniform parity: ALL buffers read [s&1], store [(s+1)&1]; pointers
//    phase-hoisted exactly like R6 (even/odd locals).
//  - paired reciprocals: 8 trans ops per update lane (was 10).
// Xstage[64][4][8]: raw-x ring, refilled 32 steps/burst every 32 ticks.
// Hbuf[3][2][4][80]: own-h of L1..L3; const-1.0 at slot 56 (bias for L2/L3
// input view; multiplies A=0 in the own view).

#define H 50
#define INSZ 7
#define TT 512
#define NL 4
#define FC1N 25
#define BPG 4
#define NBLK 256
#define NTHREADS 1024
#define HS 80        // row stride in halves (40 dw = 8 mod 32: <=2-way, free)
#define BIASL 56

typedef _Float16 half_t;
typedef __attribute__((ext_vector_type(8))) _Float16 half8_t;
typedef __attribute__((ext_vector_type(4))) float float4_t;

struct Params {
  const float* x;
  const float* Wih[NL];
  const float* Whh[NL];
  const float* bih[NL];
  const float* bhh[NL];
  const float* W1;
  const float* b1;
  const float* W2;
  const float* b2;
  float* out;
};

#define MFMA16(A, B, C) __builtin_amdgcn_mfma_f32_16x16x32_f16((A), (B), (C), 0, 0, 0)
#define EXP2F(x) __builtin_amdgcn_exp2f(x)
#define RCPF(x) __builtin_amdgcn_rcpf(x)

__global__ __launch_bounds__(NTHREADS, 4) void lstm_r8(Params p) {
  __shared__ __align__(16) half_t Xpack[2][BPG][HS];     // L0 B-row / L1 input
  __shared__ __align__(16) half_t Hbuf[3][2][BPG][HS];   // own-h L1..L3
  __shared__ __align__(16) half_t Xstage[64][BPG][8];    // raw-x ring
  __shared__ float fc_h[BPG][H];
  __shared__ float fc1_buf[BPG][FC1N];

  const int tid = threadIdx.x;
  const int b0 = blockIdx.x * BPG;
  const int lane = tid & 63;
  const int quad = lane >> 4;
  const int col = lane & 15;
  const int glay = tid >> 8;                     // layer (4 waves each)
  const int wl = (((tid >> 6) & 3) + glay) & 3;  // M-chunk, SIMD-balanced

  // ---- A fragments: row r = wl*64 + t4*16 + col (unit-major r=4u+q),
  //      k = g*32 + quad*8 + j.
  half8_t afrag[4][4];
#pragma unroll
  for (int t4 = 0; t4 < 4; ++t4) {
#pragma unroll
    for (int g = 0; g < 4; ++g) {
      half8_t v;
#pragma unroll
      for (int j = 0; j < 8; ++j) {
        const int r = wl * 64 + t4 * 16 + col;
        const int u = r >> 2, q = r & 3;
        const int k = g * 32 + quad * 8 + j;
        float wv = 0.0f;
        if (u < H) {
          const int row = q * H + u;
          if (glay == 0) {           // K=64: x 0..6, bias 7, own-h 8..57
            if (k < INSZ) wv = p.Wih[0][row * INSZ + k];
            else if (k == 7) wv = p.bih[0][row] + p.bhh[0][row];
            else if (k >= 8 && k < 8 + H) wv = p.Whh[0][row * H + (k - 8)];
          } else if (glay == 1) {    // input from Xpack: bias 7, in-h 8..57
            if (k == 7) wv = p.bih[1][row] + p.bhh[1][row];
            else if (k >= 8 && k < 8 + H) wv = p.Wih[1][row * H + (k - 8)];
            else if (k >= 64 && k < 64 + H) wv = p.Whh[1][row * H + (k - 64)];
          } else {                   // in-h 0..49, bias 56, own-h 64..113
            if (k < H) wv = p.Wih[glay][row * H + k];
            else if (k == BIASL) wv = p.bih[glay][row] + p.bhh[glay][row];
            else if (k >= 64 && k < 64 + H) wv = p.Whh[glay][row * H + (k - 64)];
          }
        }
        v[j] = (half_t)wv;
      }
      afrag[t4][g] = v;
    }
  }

  // ---- init LDS ----
  {
    unsigned* xz = (unsigned*)Xpack;
    for (int i = tid; i < 2 * BPG * HS / 2; i += NTHREADS) xz[i] = 0u;
    unsigned* hz = (unsigned*)Hbuf;
    for (int i = tid; i < 3 * 2 * BPG * HS / 2; i += NTHREADS) hz[i] = 0u;
  }
  __syncthreads();
  if (tid < 8) {  // Xpack bias-1.0 at slot 7, both parities
    Xpack[tid >> 2][tid & 3][7] = (half_t)1.0f;
  } else if (tid < 8 + 24) {  // Hbuf const-1.0 at slot 56
    const int i = tid - 8, l = i >> 3, pr = (i >> 2) & 1, b = i & 3;
    Hbuf[l][pr][b][BIASL] = (half_t)1.0f;
  }
  // ring fill t=0..63 + x(0) into Xpack[0]
  for (int i = tid; i < 64 * BPG * INSZ; i += NTHREADS) {
    const int t = i / (BPG * INSZ), rem = i % (BPG * INSZ);
    const int b = rem / INSZ, k = rem % INSZ;
    const half_t xh = (half_t)p.x[((size_t)(b0 + b) * TT + t) * INSZ + k];
    Xstage[t][b][k] = xh;
    if (t == 0) Xpack[0][b][k] = xh;
  }
  __syncthreads();

  // ---- per-lane roles ----
  const int bb = col & 3;
  const int tsel = col >> 2;
  const int uu = 16 * wl + 4 * tsel + quad;
  const bool updact = (uu < H);

  // phase-hoisted pointers: read [s&1], store [(s+1)&1].
  // pin2[ph], pown2[ph], pst2[ph] for ph = s&1.
  const half_t* pin2[2];
  const half_t* pown2[2];
  half_t* pst2[2];
  if (glay == 0) {
    pin2[0] = &Xpack[0][bb][quad * 8];
    pin2[1] = &Xpack[1][bb][quad * 8];
    pown2[0] = pin2[0];  // unused
    pown2[1] = pin2[1];
    pst2[0] = &Xpack[1][bb][8 + uu];
    pst2[1] = &Xpack[0][bb][8 + uu];
  } else if (glay == 1) {
    pin2[0] = &Xpack[0][bb][quad * 8];
    pin2[1] = &Xpack[1][bb][quad * 8];
    pown2[0] = &Hbuf[0][0][bb][quad * 8];
    pown2[1] = &Hbuf[0][1][bb][quad * 8];
    pst2[0] = &Hbuf[0][1][bb][uu];
    pst2[1] = &Hbuf[0][0][bb][uu];
  } else {
    pin2[0] = &Hbuf[glay - 2][0][bb][quad * 8];
    pin2[1] = &Hbuf[glay - 2][1][bb][quad * 8];
    pown2[0] = &Hbuf[glay - 1][0][bb][quad * 8];
    pown2[1] = &Hbuf[glay - 1][1][bb][quad * 8];
    pst2[0] = &Hbuf[glay - 1][1][bb][uu];
    pst2[1] = &Hbuf[glay - 1][0][bb][uu];
  }
  const half_t* in_e = pin2[0];
  const half_t* in_o = pin2[1];
  const half_t* own_e = pown2[0];
  const half_t* own_o = pown2[1];
  half_t* st_e = pst2[0];
  half_t* st_o = pst2[1];

  // x-copy + ring-refill role: layer-0 wl==3 wave (lightest: 2 MFMAs)
  const bool xwave = (glay == 0) && (wl == 3);
  const bool xcopy = xwave && (lane < BPG * INSZ);
  const int cb = lane / INSZ, ck = lane % INSZ;  // valid when xcopy
  const int rb = lane >> 5;                      // refill: batch pair
  const int rt = lane & 31;                      //         t offset

  float cst = 0.0f;
  const float4_t fzc = {0.0f, 0.0f, 0.0f, 0.0f};

#define TICK_BODY(PIN, POWN, PST, FCW)                                          \
  {                                                                             \
    float4_t a0 = fzc, a1 = fzc, a2 = fzc, a3 = fzc;                            \
    if (glay == 0) {                                                            \
      const half8_t v0 = *(const half8_t*)(PIN);                                \
      const half8_t v1 = *(const half8_t*)((PIN) + 32);                         \
      if (wl != 3) {                                                            \
        a0 = MFMA16(afrag[0][0], v0, a0); a1 = MFMA16(afrag[1][0], v0, a1);     \
        a2 = MFMA16(afrag[2][0], v0, a2); a3 = MFMA16(afrag[3][0], v0, a3);     \
        a0 = MFMA16(afrag[0][1], v1, a0); a1 = MFMA16(afrag[1][1], v1, a1);     \
        a2 = MFMA16(afrag[2][1], v1, a2); a3 = MFMA16(afrag[3][1], v1, a3);     \
      } else {                                                                  \
        a0 = MFMA16(afrag[0][0], v0, a0);                                       \
        a0 = MFMA16(afrag[0][1], v1, a0);                                       \
      }                                                                         \
    } else {                                                                    \
      const half8_t v0 = *(const half8_t*)(PIN);                                \
      const half8_t v1 = *(const half8_t*)((PIN) + 32);                         \
      const half8_t v2 = *(const half8_t*)(POWN);                               \
      const half8_t v3 = *(const half8_t*)((POWN) + 32);                        \
      if (wl != 3) {                                                            \
        a0 = MFMA16(afrag[0][0], v0, a0); a1 = MFMA16(afrag[1][0], v0, a1);     \
        a2 = MFMA16(afrag[2][0], v0, a2); a3 = MFMA16(afrag[3][0], v0, a3);     \
        a0 = MFMA16(afrag[0][1], v1, a0); a1 = MFMA16(afrag[1][1], v1, a1);     \
        a2 = MFMA16(afrag[2][1], v1, a2); a3 = MFMA16(afrag[3][1], v1, a3);     \
        a0 = MFMA16(afrag[0][2], v2, a0); a1 = MFMA16(afrag[1][2], v2, a1);     \
        a2 = MFMA16(afrag[2][2], v2, a2); a3 = MFMA16(afrag[3][2], v2, a3);     \
        a0 = MFMA16(afrag[0][3], v3, a0); a1 = MFMA16(afrag[1][3], v3, a1);     \
        a2 = MFMA16(afrag[2][3], v3, a2); a3 = MFMA16(afrag[3][3], v3, a3);     \
      } else {                                                                  \
        a0 = MFMA16(afrag[0][0], v0, a0);                                       \
        a0 = MFMA16(afrag[0][1], v1, a0);                                       \
        a0 = MFMA16(afrag[0][2], v2, a0);                                       \
        a0 = MFMA16(afrag[0][3], v3, a0);                                       \
      }                                                                         \
    }                                                                           \
    if (updact) {                                                               \
      const float4_t g01 = (col & 4) ? a1 : a0;                                 \
      const float4_t g23 = (col & 4) ? a3 : a2;                                 \
      const float4_t ga = (col & 8) ? g23 : g01;                                \
      const float di = 1.0f + EXP2F(-1.442695041f * ga[0]);                     \
      const float df = 1.0f + EXP2F(-1.442695041f * ga[1]);                     \
      const float dg = 1.0f + EXP2F(-2.885390082f * ga[2]);                     \
      const float dq = 1.0f + EXP2F(-1.442695041f * ga[3]);                     \
      const float r1 = RCPF(di * df);                                           \
      const float r2 = RCPF(dg * dq);                                           \
      const float gi = r1 * df;                                                 \
      const float gf = r1 * di;                                                 \
      const float gg = 2.0f * (r2 * dq) - 1.0f;                                 \
      const float go = r2 * dg;                                                 \
      cst = gf * cst + gi * gg;                                                 \
      const float dc = 1.0f + EXP2F(-2.885390082f * cst);                       \
      const float h = go * (2.0f * RCPF(dc) - 1.0f);                            \
      *(PST) = (half_t)h;                                                       \
      if (FCW) fc_h[bb][uu] = h;                                                \
    }                                                                           \
  }

  // x-copy: ring row (s+1) -> Xpack[(s+1)&1] slots 0..6 (one light wave)
#define XCOPY(S)                                                                \
  if (xcopy) {                                                                  \
    const int tn = (S) + 1;                                                     \
    Xpack[tn & 1][cb][ck] = Xstage[tn & 63][cb][ck];                            \
  }

  // ---- prologue: s = 0..2 (guarded, dynamic parity) ----
  for (int s = 0; s < 3; ++s) {
    const int t = s - glay;
    if (t >= 0) {
      const int ph = s & 1;
      TICK_BODY(pin2[ph], pown2[ph], pst2[ph], false)
    }
    XCOPY(s)
    __syncthreads();
  }

  // ---- steady: s = 3..510, unrolled x2, compile-time phase ----
  for (int s = 3; s < 511; s += 2) {
    {  // odd tick s (ph=1)
      TICK_BODY(in_o, own_o, st_o, false)
      XCOPY(s)
    }
    __syncthreads();
    {  // even tick s+1 (ph=0)
      const int s2 = s + 1;
      if (xwave && (s2 & 31) == 8 && s2 < 480) {  // ring refill burst
        const int tb = (s2 & ~31) + 32;
#pragma unroll
        for (int pp = 0; pp < 2; ++pp) {
          const int b = rb + 2 * pp;
          const int t = tb + rt;
          const float* src = &p.x[((size_t)(b0 + b) * TT + t) * INSZ];
          half_t* dst = &Xstage[t & 63][b][0];
#pragma unroll
          for (int k = 0; k < INSZ; ++k) dst[k] = (half_t)src[k];
        }
      }
      TICK_BODY(in_e, own_e, st_e, false)
      XCOPY(s2)
    }
    __syncthreads();
  }

  // ---- tail: s = 511..514 (guarded; no x-copy) ----
  for (int s = 511; s < TT + NL - 1; ++s) {
    const int t = s - glay;
    if (t < TT) {
      const int ph = s & 1;
      const bool fcw = (glay == NL - 1) && (t == TT - 1);
      TICK_BODY(pin2[ph], pown2[ph], pst2[ph], fcw)
    }
    __syncthreads();
  }

  // ---- FC head (fp32) ----
  if (tid < BPG * FC1N) {
    const int b = tid / FC1N, j = tid % FC1N;
    const float* w = p.W1 + j * H;
    float a = p.b1[j];
#pragma unroll
    for (int k = 0; k < H; ++k) a += fc_h[b][k] * w[k];
    fc1_buf[b][j] = fmaxf(a, 0.0f);
  }
  __syncthreads();
  if (tid < BPG) {
    float a = p.b2[0];
#pragma unroll
    for (int j = 0; j < FC1N; ++j) a += fc1_buf[tid][j] * p.W2[j];
    p.out[b0 + tid] = a;
  }
}

extern "C" void kernel_launch(void* const* d_in, const int* in_sizes, int n_in,
                              void* d_out, int out_size, void* d_ws, size_t ws_size,
                              hipStream_t stream) {
  Params p;
  p.x = (const float*)d_in[0];
  for (int l = 0; l < NL; ++l) {
    p.Wih[l] = (const float*)d_in[1 + 4 * l];
    p.Whh[l] = (const float*)d_in[2 + 4 * l];
    p.bih[l] = (const float*)d_in[3 + 4 * l];
    p.bhh[l] = (const float*)d_in[4 + 4 * l];
  }
  p.W1 = (const float*)d_in[17];
  p.b1 = (const float*)d_in[18];
  p.W2 = (const float*)d_in[19];
  p.b2 = (const float*)d_in[20];
  p.out = (float*)d_out;

  hipLaunchKernelGGL(lstm_r8, dim3(NBLK), dim3(NTHREADS), 0, stream, p);
}